// Round 6
// baseline (139.592 us; speedup 1.0000x reference)
//
#include <hip/hip_runtime.h>
#include <hip/hip_fp16.h>

#define EPS 1e-7f

// ---------------------------------------------------------------------------
// Fused Phase 1 (512 thr): blocks [0,binBlocks) bin 2048 edges each into
// 256-node coarse buckets (fixed-capacity windows, LDS-ranked -> contiguous
// runs); blocks [binBlocks,...) build fp16 table tm[n][c] = relu(x)+eps with
// sentinel row N = -32 (exp(beta*-32)~1e-14: padding contributes ~0).
// Packed entry: (dst&255)<<16 | src  (needs N < 65536).
// ---------------------------------------------------------------------------
__global__ __launch_bounds__(512)
void binprep_kernel(const int* __restrict__ dst,
                    const int* __restrict__ src, int E, int cap,
                    const float* __restrict__ x, int M,
                    int* __restrict__ ccur,
                    unsigned* __restrict__ packed,
                    unsigned short* __restrict__ tm,
                    int binBlocks) {
    if ((int)blockIdx.x < binBlocks) {
        __shared__ int lc[256];
        __shared__ int lbase[256];
        int tid = threadIdx.x;
        if (tid < 256) lc[tid] = 0;
        __syncthreads();
        int e0 = blockIdx.x * 2048;
        int bb[4], rr[4];
        unsigned pk[4];
        #pragma unroll
        for (int i = 0; i < 4; ++i) {
            int e = e0 + i * 512 + tid;
            bb[i] = 0; rr[i] = 0; pk[i] = 0;
            if (e < E) {
                int d = dst[e];
                bb[i] = d >> 8;
                pk[i] = ((unsigned)(d & 255) << 16) | (unsigned)src[e];
                rr[i] = atomicAdd(&lc[bb[i]], 1);
            }
        }
        __syncthreads();
        if (tid < 256) {
            int c = lc[tid];
            if (c) lbase[tid] = tid * cap + atomicAdd(&ccur[tid], c);
        }
        __syncthreads();
        #pragma unroll
        for (int i = 0; i < 4; ++i) {
            int e = e0 + i * 512 + tid;
            if (e < E) packed[lbase[bb[i]] + rr[i]] = pk[i];
        }
    } else {
        int blk = blockIdx.x - binBlocks;
        int tid = threadIdx.x;
        const unsigned short sent = __half_as_ushort(__float2half_rn(-32.f));
        #pragma unroll
        for (int p = 0; p < 4; ++p) {
            int i = blk * 8192 + p * 2048 + tid * 4;
            if (i < M) {
                float4 v = *(const float4*)&x[i];
                ushort4 o;
                o.x = __half_as_ushort(__float2half_rn(fmaxf(v.x, 0.f) + EPS));
                o.y = __half_as_ushort(__float2half_rn(fmaxf(v.y, 0.f) + EPS));
                o.z = __half_as_ushort(__float2half_rn(fmaxf(v.z, 0.f) + EPS));
                o.w = __half_as_ushort(__float2half_rn(fmaxf(v.w, 0.f) + EPS));
                *(ushort4*)&tm[i] = o;
            } else if (i < M + 64) {
                ushort4 o; o.x = o.y = o.z = o.w = sent;
                *(ushort4*)&tm[i] = o;
            }
        }
    }
}

// ---------------------------------------------------------------------------
// Phase 2 (512 thr): one block per bucket. Stage packed window in LDS;
// in-LDS hist of dst-low-byte -> 256-wide scan (first 4 waves) -> per-node
// (start,end) int2 + LDS fine scatter, then coalesced u32-pair write.
// ---------------------------------------------------------------------------
__global__ __launch_bounds__(512)
void fine_kernel(const unsigned* __restrict__ packed,
                 const int* __restrict__ ccur, int cap,
                 int2* __restrict__ nse,
                 unsigned short* __restrict__ sorted_src, int N) {
    __shared__ int lc[256];
    __shared__ int lcur[256];
    __shared__ int wsum[4];
    __shared__ unsigned stage_pk[6656];
    __shared__ unsigned short stage16[6656];
    int tid = threadIdx.x, b = blockIdx.x;
    int rs = b * cap;
    int len = ccur[b];
    if (tid < 256) lc[tid] = 0;
    __syncthreads();
    for (int i = tid; i < len; i += 512) {
        unsigned u = packed[rs + i];
        stage_pk[i] = u;
        atomicAdd(&lc[u >> 16], 1);
    }
    __syncthreads();
    // 256-wide scan on first 4 waves: phase 1 (per-wave inclusive -> lcur)
    if (tid < 256) {
        int lane = tid & 63, wid = tid >> 6;
        int incl = lc[tid];
        #pragma unroll
        for (int d = 1; d < 64; d <<= 1) {
            int t = __shfl_up(incl, d, 64);
            if (lane >= d) incl += t;
        }
        lcur[tid] = incl;
        if (lane == 63) wsum[wid] = incl;
    }
    __syncthreads();
    // phase 2: add wave bases -> exclusive; emit nse
    if (tid < 256) {
        int wid = tid >> 6;
        int base = 0;
        for (int w = 0; w < wid; ++w) base += wsum[w];
        int v = lc[tid];
        int excl = base + lcur[tid] - v;
        lcur[tid] = excl;
        int node = b * 256 + tid;
        if (node < N) nse[node] = make_int2(rs + excl, rs + excl + v);
    }
    __syncthreads();
    for (int i = tid; i < len; i += 512) {
        unsigned u = stage_pk[i];
        int pos = atomicAdd(&lcur[u >> 16], 1);
        stage16[pos] = (unsigned short)(u & 0xffffu);
    }
    __syncthreads();
    // coalesced copy out (rs is 256-aligned -> u32 writes aligned)
    unsigned* dst32 = (unsigned*)&sorted_src[rs];
    int len2 = (len + 1) >> 1;
    for (int i = tid; i < len2; i += 512) {
        unsigned lo = stage16[2 * i];
        unsigned hi = (2 * i + 1 < len) ? (unsigned)stage16[2 * i + 1] : 0u;
        dst32[i] = lo | (hi << 16);
    }
}

// ---------------------------------------------------------------------------
// Per-node fused softmax-aggregate + linear. 512 threads = 8 waves share one
// WtS (halves LDS/wave -> 4 blocks/CU, 32 waves/CU). Quarter-wave gather:
// lane owns channels 4*(lane&15)..+3 (one dwordx2 of fp16 m); 2-deep
// software pipeline keeps >=4 gathers in flight per wave. exp computed
// in-register; shfl_xor(16,32) combines quarters.
// ---------------------------------------------------------------------------
__device__ __forceinline__ void acc2(unsigned w, float bt,
                                     float& s1a, float& s2a,
                                     float& s1b, float& s2b) {
    float m0 = __half2float(__ushort_as_half((unsigned short)(w & 0xffffu)));
    float m1 = __half2float(__ushort_as_half((unsigned short)(w >> 16)));
    float e0 = __expf(bt * m0);
    float e1 = __expf(bt * m1);
    s1a += e0; s2a = fmaf(m0, e0, s2a);
    s1b += e1; s2b = fmaf(m1, e1, s2b);
}

__global__ __launch_bounds__(512)
void node_kernel(const unsigned short* __restrict__ tm,
                 const int2* __restrict__ nse,
                 const unsigned short* __restrict__ sorted_src,
                 const float* __restrict__ W,
                 const float* __restrict__ b,
                 const float* __restrict__ beta,
                 float* __restrict__ out, int N) {
    __shared__ float WtS[64 * 65];   // stride 65: 2-way bank alias = free
    __shared__ float aggS[512];

    int tid = threadIdx.x;
    #pragma unroll
    for (int idx = tid * 4; idx < 64 * 64; idx += 512 * 4) {
        float4 w4 = *(const float4*)&W[idx];
        int j = idx >> 6, c = idx & 63;
        WtS[(c + 0) * 65 + j] = w4.x;
        WtS[(c + 1) * 65 + j] = w4.y;
        WtS[(c + 2) * 65 + j] = w4.z;
        WtS[(c + 3) * 65 + j] = w4.w;
    }
    __syncthreads();

    const float bt = beta[0];
    const int wave = tid >> 6;
    const int lane = tid & 63;
    const int quarter = lane >> 4;
    const int chb = (lane & 15) << 3;      // byte offset of channel quad
    const float bias = b[lane];
    const int stride = gridDim.x * 8;
    const int sent_row = N << 7;           // byte offset of sentinel row
    const unsigned char* tmb = (const unsigned char*)tm;
    float* as = &aggS[wave * 64];          // wave-private

    for (int node = blockIdx.x * 8 + wave; node < N; node += stride) {
        int2 se = nse[node];
        int start = se.x, end = se.y;
        float s1c0 = 0.f, s1c1 = 0.f, s1c2 = 0.f, s1c3 = 0.f;
        float s2c0 = 0.f, s2c1 = 0.f, s2c2 = 0.f, s2c3 = 0.f;
        for (int bse = start; bse < end; bse += 64) {
            int cnt = end - bse;
            if (cnt > 64) cnt = 64;
            int row = (lane < cnt) ? ((int)sorted_src[bse + lane] << 7)
                                   : sent_row;
            // 2-deep pipeline: current pair in u0/u1, next pair prefetched
            int r0 = __shfl(row, quarter, 64);
            int r1 = __shfl(row, 4 + quarter, 64);
            uint2 u0 = *(const uint2*)(tmb + (r0 + chb));
            uint2 u1 = *(const uint2*)(tmb + (r1 + chb));
            int k = 0;
            while (k + 8 < cnt) {
                int n0 = __shfl(row, k + 8 + quarter, 64);
                int n1 = __shfl(row, k + 12 + quarter, 64);
                uint2 v0 = *(const uint2*)(tmb + (n0 + chb));
                uint2 v1 = *(const uint2*)(tmb + (n1 + chb));
                acc2(u0.x, bt, s1c0, s2c0, s1c1, s2c1);
                acc2(u0.y, bt, s1c2, s2c2, s1c3, s2c3);
                acc2(u1.x, bt, s1c0, s2c0, s1c1, s2c1);
                acc2(u1.y, bt, s1c2, s2c2, s1c3, s2c3);
                u0 = v0; u1 = v1;
                k += 8;
            }
            acc2(u0.x, bt, s1c0, s2c0, s1c1, s2c1);
            acc2(u0.y, bt, s1c2, s2c2, s1c3, s2c3);
            acc2(u1.x, bt, s1c0, s2c0, s1c1, s2c1);
            acc2(u1.y, bt, s1c2, s2c2, s1c3, s2c3);
        }
        // combine the 4 quarters
        #define RED(s) s += __shfl_xor(s, 16, 64); s += __shfl_xor(s, 32, 64)
        RED(s1c0); RED(s1c1); RED(s1c2); RED(s1c3);
        RED(s2c0); RED(s2c1); RED(s2c2); RED(s2c3);
        #undef RED
        float4 g;
        g.x = __fdividef(s2c0, s1c0 + 1e-16f);
        g.y = __fdividef(s2c1, s1c1 + 1e-16f);
        g.z = __fdividef(s2c2, s1c2 + 1e-16f);
        g.w = __fdividef(s2c3, s1c3 + 1e-16f);
        if (lane < 16) *(float4*)&as[(lane & 15) << 2] = g;
        float acc = bias;
        #pragma unroll
        for (int c = 0; c < 64; c += 4) {
            float4 a4 = *(const float4*)&as[c];  // uniform addr -> broadcast
            acc = fmaf(a4.x, WtS[(c + 0) * 65 + lane], acc);
            acc = fmaf(a4.y, WtS[(c + 1) * 65 + lane], acc);
            acc = fmaf(a4.z, WtS[(c + 2) * 65 + lane], acc);
            acc = fmaf(a4.w, WtS[(c + 3) * 65 + lane], acc);
        }
        out[(size_t)node * 64 + lane] = acc;
    }
}

// ---------------------------------------------------------------------------
// launch
// ---------------------------------------------------------------------------
extern "C" void kernel_launch(void* const* d_in, const int* in_sizes, int n_in,
                              void* d_out, int out_size, void* d_ws, size_t ws_size,
                              hipStream_t stream) {
    const float* x    = (const float*)d_in[0];
    const int*   ei   = (const int*)d_in[1];    // [2, E]: row0 = dst, row1 = src
    const float* W    = (const float*)d_in[2];
    const float* b    = (const float*)d_in[3];
    const float* beta = (const float*)d_in[4];
    float* out = (float*)d_out;

    const int N = in_sizes[0] / 64;
    const int E = in_sizes[1] / 2;
    const int* dst = ei;
    const int* src = ei + E;
    const int NB = (N + 255) >> 8;              // 196 coarse buckets
    const int M = N * 64;

    // fixed per-bucket capacity: mean + 50% + 256, rounded up to 256 (<=6656)
    int cap = (E + NB - 1) / NB;
    cap = ((cap + cap / 2 + 256) + 255) & ~255;
    if (cap > 6656) cap = 6656;

    auto align = [](size_t v) { return (v + 255) & ~(size_t)255; };
    size_t off = 0;
    char* ws = (char*)d_ws;
    int2* nse   = (int2*)(ws + off);      off += align((size_t)N * 8);
    int* ccur   = (int*)(ws + off);       off += align((size_t)NB * 4);
    unsigned* packed = (unsigned*)(ws + off);
    off += align((size_t)NB * cap * 4);
    unsigned short* sorted_src = (unsigned short*)(ws + off);
    off += align((size_t)NB * cap * 2);
    unsigned short* tm = (unsigned short*)(ws + off);  // (N+1)*64 fp16

    const int binBlocks  = (E + 2047) / 2048;          // 391
    const int prepBlocks = (M + 64 + 8191) / 8192;     // 391
    hipMemsetAsync(ccur, 0, (size_t)NB * 4, stream);
    binprep_kernel<<<binBlocks + prepBlocks, 512, 0, stream>>>(
        dst, src, E, cap, x, M, ccur, packed, tm, binBlocks);
    fine_kernel<<<NB, 512, 0, stream>>>(packed, ccur, cap, nse, sorted_src, N);

    int node_blocks = (N + 7) / 8;
    if (node_blocks > 1024) node_blocks = 1024;  // 4 blocks/CU, 32 waves/CU
    node_kernel<<<node_blocks, 512, 0, stream>>>(tm, nse, sorted_src,
                                                 W, b, beta, out, N);
}

// Round 7
// 133.573 us; speedup vs baseline: 1.0451x; 1.0451x over previous
//
#include <hip/hip_runtime.h>
#include <hip/hip_fp16.h>

#define EPS 1e-7f

// ---------------------------------------------------------------------------
// Fused Phase 1 (512 thr): blocks [0,binBlocks) bin 2048 edges each into
// 256-node coarse buckets (fixed-capacity windows, LDS-ranked -> contiguous
// runs). Blocks [binBlocks,...) build u32 table tp[n][c] = pack(fp16 ex,
// fp16 m*ex), ex = exp(beta*m), m = relu(x)+eps. Row N = zeros (sentinel:
// padding contributes exactly 0 to both softmax sums).
// Packed edge entry: (dst&255)<<16 | src  (needs N < 65536).
// ---------------------------------------------------------------------------
__global__ __launch_bounds__(512)
void binprep_kernel(const int* __restrict__ dst,
                    const int* __restrict__ src, int E, int cap,
                    const float* __restrict__ x,
                    const float* __restrict__ beta, int M,
                    int* __restrict__ ccur,
                    unsigned* __restrict__ packed,
                    unsigned* __restrict__ tp,
                    int binBlocks) {
    if ((int)blockIdx.x < binBlocks) {
        __shared__ int lc[256];
        __shared__ int lbase[256];
        int tid = threadIdx.x;
        if (tid < 256) lc[tid] = 0;
        __syncthreads();
        int e0 = blockIdx.x * 2048;
        int bb[4], rr[4];
        unsigned pk[4];
        #pragma unroll
        for (int i = 0; i < 4; ++i) {
            int e = e0 + i * 512 + tid;
            bb[i] = 0; rr[i] = 0; pk[i] = 0;
            if (e < E) {
                int d = dst[e];
                bb[i] = d >> 8;
                pk[i] = ((unsigned)(d & 255) << 16) | (unsigned)src[e];
                rr[i] = atomicAdd(&lc[bb[i]], 1);
            }
        }
        __syncthreads();
        if (tid < 256) {
            int c = lc[tid];
            if (c) lbase[tid] = tid * cap + atomicAdd(&ccur[tid], c);
        }
        __syncthreads();
        #pragma unroll
        for (int i = 0; i < 4; ++i) {
            int e = e0 + i * 512 + tid;
            if (e < E) packed[lbase[bb[i]] + rr[i]] = pk[i];
        }
    } else {
        int blk = blockIdx.x - binBlocks;
        int tid = threadIdx.x;
        const float bt = beta[0];
        #pragma unroll
        for (int p = 0; p < 4; ++p) {
            int i = blk * 8192 + p * 2048 + tid * 4;
            if (i < M) {
                float4 v = *(const float4*)&x[i];
                uint4 o;
                float m, ex;
                m = fmaxf(v.x, 0.f) + EPS; ex = __expf(bt * m);
                o.x = (unsigned)__half_as_ushort(__float2half_rn(ex)) |
                      ((unsigned)__half_as_ushort(__float2half_rn(m * ex)) << 16);
                m = fmaxf(v.y, 0.f) + EPS; ex = __expf(bt * m);
                o.y = (unsigned)__half_as_ushort(__float2half_rn(ex)) |
                      ((unsigned)__half_as_ushort(__float2half_rn(m * ex)) << 16);
                m = fmaxf(v.z, 0.f) + EPS; ex = __expf(bt * m);
                o.z = (unsigned)__half_as_ushort(__float2half_rn(ex)) |
                      ((unsigned)__half_as_ushort(__float2half_rn(m * ex)) << 16);
                m = fmaxf(v.w, 0.f) + EPS; ex = __expf(bt * m);
                o.w = (unsigned)__half_as_ushort(__float2half_rn(ex)) |
                      ((unsigned)__half_as_ushort(__float2half_rn(m * ex)) << 16);
                *(uint4*)&tp[i] = o;
            } else if (i < M + 64) {
                uint4 o; o.x = o.y = o.z = o.w = 0u;
                *(uint4*)&tp[i] = o;
            }
        }
    }
}

// ---------------------------------------------------------------------------
// Phase 2 (512 thr): one block per bucket. Stage packed window in LDS;
// in-LDS hist of dst-low-byte -> 256-wide scan -> per-node (start,end) int2 +
// LDS fine scatter, then coalesced u32-pair write of u16 sorted_src.
// ---------------------------------------------------------------------------
__global__ __launch_bounds__(512)
void fine_kernel(const unsigned* __restrict__ packed,
                 const int* __restrict__ ccur, int cap,
                 int2* __restrict__ nse,
                 unsigned short* __restrict__ sorted_src, int N) {
    __shared__ int lc[256];
    __shared__ int lcur[256];
    __shared__ int wsum[4];
    __shared__ unsigned stage_pk[6656];
    __shared__ unsigned short stage16[6656];
    int tid = threadIdx.x, b = blockIdx.x;
    int rs = b * cap;
    int len = ccur[b];
    if (tid < 256) lc[tid] = 0;
    __syncthreads();
    for (int i = tid; i < len; i += 512) {
        unsigned u = packed[rs + i];
        stage_pk[i] = u;
        atomicAdd(&lc[u >> 16], 1);
    }
    __syncthreads();
    if (tid < 256) {
        int lane = tid & 63, wid = tid >> 6;
        int incl = lc[tid];
        #pragma unroll
        for (int d = 1; d < 64; d <<= 1) {
            int t = __shfl_up(incl, d, 64);
            if (lane >= d) incl += t;
        }
        lcur[tid] = incl;
        if (lane == 63) wsum[wid] = incl;
    }
    __syncthreads();
    if (tid < 256) {
        int wid = tid >> 6;
        int base = 0;
        for (int w = 0; w < wid; ++w) base += wsum[w];
        int v = lc[tid];
        int excl = base + lcur[tid] - v;
        lcur[tid] = excl;
        int node = b * 256 + tid;
        if (node < N) nse[node] = make_int2(rs + excl, rs + excl + v);
    }
    __syncthreads();
    for (int i = tid; i < len; i += 512) {
        unsigned u = stage_pk[i];
        int pos = atomicAdd(&lcur[u >> 16], 1);
        stage16[pos] = (unsigned short)(u & 0xffffu);
    }
    __syncthreads();
    unsigned* dst32 = (unsigned*)&sorted_src[rs];
    int len2 = (len + 1) >> 1;
    for (int i = tid; i < len2; i += 512) {
        unsigned lo = stage16[2 * i];
        unsigned hi = (2 * i + 1 < len) ? (unsigned)stage16[2 * i + 1] : 0u;
        dst32[i] = lo | (hi << 16);
    }
}

// ---------------------------------------------------------------------------
// Softmax-aggregate: QUARTER-WAVE PER NODE. 16 lanes x 16B = one full 256B
// table row; lane owns channels 4*(lane&15)..+3 of its quarter's node.
// No cross-lane reduction, no LDS, direct float4 agg write. Inner loop:
// 4 independent dwordx4 gathers in flight; table holds precomputed
// (fp16 ex, fp16 m*ex) so accumulate is cvt+add only. Sentinel row (zeros)
// absorbs all padding.
// ---------------------------------------------------------------------------
__device__ __forceinline__ float f16lo(unsigned w) {
    return __half2float(__ushort_as_half((unsigned short)(w & 0xffffu)));
}
__device__ __forceinline__ float f16hi(unsigned w) {
    return __half2float(__ushort_as_half((unsigned short)(w >> 16)));
}

__global__ __launch_bounds__(256)
void node_kernel(const unsigned* __restrict__ tp,
                 const int2* __restrict__ nse,
                 const unsigned short* __restrict__ ss,
                 float* __restrict__ agg, int N) {
    const int tid = threadIdx.x;
    const int wave = tid >> 6;
    const int lane = tid & 63;
    const int quarter = lane >> 4;
    const int l16 = lane & 15;
    const int qbase = quarter << 4;
    const int chb = l16 << 4;            // byte offset of channel quad
    const int sent = N << 8;             // sentinel row byte offset (zeros)
    const unsigned char* tb = (const unsigned char*)tp;

    const int node = blockIdx.x * 16 + wave * 4 + quarter;
    int start = 0, cnt = 0;
    if (node < N) { int2 se = nse[node]; start = se.x; cnt = se.y - se.x; }

    float s1x = 0.f, s1y = 0.f, s1z = 0.f, s1w = 0.f;
    float s2x = 0.f, s2y = 0.f, s2z = 0.f, s2w = 0.f;

    for (int chunk = 0; chunk < cnt; chunk += 16) {
        int rem = cnt - chunk;
        if (rem > 16) rem = 16;
        // lane j of this quarter holds edge (chunk+j)'s row byte-offset
        int row = (l16 < rem) ? ((int)ss[start + chunk + l16] << 8) : sent;
        for (int k = 0; k < rem; k += 4) {
            // k in {0,4,8,12}; k+3 <= 15 -> shfl index stays in-quarter
            int r0 = __shfl(row, qbase + k + 0, 64);
            int r1 = __shfl(row, qbase + k + 1, 64);
            int r2 = __shfl(row, qbase + k + 2, 64);
            int r3 = __shfl(row, qbase + k + 3, 64);
            uint4 u0 = *(const uint4*)(tb + (r0 + chb));
            uint4 u1 = *(const uint4*)(tb + (r1 + chb));
            uint4 u2 = *(const uint4*)(tb + (r2 + chb));
            uint4 u3 = *(const uint4*)(tb + (r3 + chb));
            #define ACC(u) \
                s1x += f16lo(u.x); s2x += f16hi(u.x); \
                s1y += f16lo(u.y); s2y += f16hi(u.y); \
                s1z += f16lo(u.z); s2z += f16hi(u.z); \
                s1w += f16lo(u.w); s2w += f16hi(u.w)
            ACC(u0); ACC(u1); ACC(u2); ACC(u3);
            #undef ACC
        }
    }
    if (node < N) {
        float4 g;
        g.x = __fdividef(s2x, s1x + 1e-16f);
        g.y = __fdividef(s2y, s1y + 1e-16f);
        g.z = __fdividef(s2z, s1z + 1e-16f);
        g.w = __fdividef(s2w, s1w + 1e-16f);
        *(float4*)&agg[((size_t)node << 6) + (l16 << 2)] = g;
    }
}

// ---------------------------------------------------------------------------
// Final linear: out = agg @ W^T + b. W staged to LDS once per block
// (stride 65 -> free 2-way bank aliasing), wave per node, grid-stride.
// ---------------------------------------------------------------------------
__global__ __launch_bounds__(256)
void linear_kernel(const float* __restrict__ agg,
                   const float* __restrict__ W,
                   const float* __restrict__ b,
                   float* __restrict__ out, int N) {
    __shared__ float WtS[64 * 65];
    __shared__ float aggS[256];
    int tid = threadIdx.x;
    #pragma unroll
    for (int idx = tid * 4; idx < 64 * 64; idx += 256 * 4) {
        float4 w4 = *(const float4*)&W[idx];
        int j = idx >> 6, c = idx & 63;
        WtS[(c + 0) * 65 + j] = w4.x;
        WtS[(c + 1) * 65 + j] = w4.y;
        WtS[(c + 2) * 65 + j] = w4.z;
        WtS[(c + 3) * 65 + j] = w4.w;
    }
    __syncthreads();
    const int wave = tid >> 6;
    const int lane = tid & 63;
    const float bias = b[lane];
    const int stride = gridDim.x * 4;
    float* as = &aggS[wave * 64];  // wave-private; in-order DS pipe
    for (int node = blockIdx.x * 4 + wave; node < N; node += stride) {
        as[lane] = agg[(size_t)node * 64 + lane];
        float acc = bias;
        #pragma unroll
        for (int c = 0; c < 64; c += 4) {
            float4 a4 = *(const float4*)&as[c];  // uniform addr -> broadcast
            acc = fmaf(a4.x, WtS[(c + 0) * 65 + lane], acc);
            acc = fmaf(a4.y, WtS[(c + 1) * 65 + lane], acc);
            acc = fmaf(a4.z, WtS[(c + 2) * 65 + lane], acc);
            acc = fmaf(a4.w, WtS[(c + 3) * 65 + lane], acc);
        }
        out[(size_t)node * 64 + lane] = acc;
    }
}

// ---------------------------------------------------------------------------
// launch
// ---------------------------------------------------------------------------
extern "C" void kernel_launch(void* const* d_in, const int* in_sizes, int n_in,
                              void* d_out, int out_size, void* d_ws, size_t ws_size,
                              hipStream_t stream) {
    const float* x    = (const float*)d_in[0];
    const int*   ei   = (const int*)d_in[1];    // [2, E]: row0 = dst, row1 = src
    const float* W    = (const float*)d_in[2];
    const float* b    = (const float*)d_in[3];
    const float* beta = (const float*)d_in[4];
    float* out = (float*)d_out;

    const int N = in_sizes[0] / 64;
    const int E = in_sizes[1] / 2;
    const int* dst = ei;
    const int* src = ei + E;
    const int NB = (N + 255) >> 8;              // 196 coarse buckets
    const int M = N * 64;

    // fixed per-bucket capacity: mean + 50% + 256, rounded up to 256 (<=6656)
    int cap = (E + NB - 1) / NB;
    cap = ((cap + cap / 2 + 256) + 255) & ~255;
    if (cap > 6656) cap = 6656;

    auto align = [](size_t v) { return (v + 255) & ~(size_t)255; };
    size_t off = 0;
    char* ws = (char*)d_ws;
    int2* nse   = (int2*)(ws + off);      off += align((size_t)N * 8);
    int* ccur   = (int*)(ws + off);       off += align((size_t)NB * 4);
    unsigned* packed = (unsigned*)(ws + off);
    off += align((size_t)NB * cap * 4);
    unsigned short* sorted_src = (unsigned short*)(ws + off);
    off += align((size_t)NB * cap * 2);
    unsigned* tp = (unsigned*)(ws + off); off += align(((size_t)N + 1) * 64 * 4);
    float* agg  = (float*)(ws + off);     off += align((size_t)M * 4);

    const int binBlocks  = (E + 2047) / 2048;
    const int prepBlocks = (M + 64 + 8191) / 8192;
    hipMemsetAsync(ccur, 0, (size_t)NB * 4, stream);
    binprep_kernel<<<binBlocks + prepBlocks, 512, 0, stream>>>(
        dst, src, E, cap, x, beta, M, ccur, packed, tp, binBlocks);
    fine_kernel<<<NB, 512, 0, stream>>>(packed, ccur, cap, nse, sorted_src, N);
    node_kernel<<<(N + 15) / 16, 256, 0, stream>>>(tp, nse, sorted_src, agg, N);

    int lin_blocks = (N + 3) / 4;
    if (lin_blocks > 2048) lin_blocks = 2048;
    linear_kernel<<<lin_blocks, 256, 0, stream>>>(agg, W, b, out, N);
}